// Round 1
// baseline (12886.777 us; speedup 1.0000x reference)
//
#include <hip/hip_runtime.h>

#define T_SEQ 512
#define BATCH 128
#define D_IN  1024
#define D_OUT 1024
#define D_XH  2048

typedef __bf16 bf16_t;
typedef __bf16 bf16x8 __attribute__((ext_vector_type(8)));
typedef float  f32x4  __attribute__((ext_vector_type(4)));

// ---------------- workspace layout (bytes) ----------------
// Wpk  bf16 fragment-packed [64 dblk][4 g][64 ks][64 lane][8] : 0 .. 16,777,216
// hbuf bf16 [2][128][1024] ping-pong                          : +524,288
// bar  u32  8 shard counters (128 B apart) + root             : +2,048
#define WS_WPK 0
#define WS_H   16777216
#define WS_BAR (WS_H + 2 * BATCH * D_OUT * 2)

__device__ __forceinline__ float sigm(float x)   { return 1.0f / (1.0f + __expf(-x)); }
__device__ __forceinline__ float tanh_f(float x) { return 2.0f / (1.0f + __expf(-2.0f * x)) - 1.0f; }

// Pack gate weights fp32 [1024][2048] (x4) into MFMA-fragment order bf16:
// elem offset = (((dblk*4+g)*64 + ks)*64 + lane)*8
// holding W[row = dblk*16+(lane&15)][col = ks*32+(lane>>4)*8 .. +8)
__global__ void pack_weights(const float* __restrict__ Wf, const float* __restrict__ Wi,
                             const float* __restrict__ Wc, const float* __restrict__ Wo,
                             bf16_t* __restrict__ Wpk) {
    int o = blockIdx.x * 256 + threadIdx.x;          // 0 .. 1048575
    int gd   = o >> 12;                              // dblk*4 + g
    int ks   = (o >> 6) & 63;
    int lane = o & 63;
    int dblk = gd >> 2, g = gd & 3;
    int row  = dblk * 16 + (lane & 15);
    int col  = ks * 32 + (lane >> 4) * 8;
    const float* W = (g == 0) ? Wf : (g == 1) ? Wi : (g == 2) ? Wc : Wo;
    const float* s = W + (size_t)row * D_XH + col;
    float4 v0 = *(const float4*)s;
    float4 v1 = *(const float4*)(s + 4);
    bf16x8 w;
    w[0] = (bf16_t)v0.x; w[1] = (bf16_t)v0.y; w[2] = (bf16_t)v0.z; w[3] = (bf16_t)v0.w;
    w[4] = (bf16_t)v1.x; w[5] = (bf16_t)v1.y; w[6] = (bf16_t)v1.z; w[7] = (bf16_t)v1.w;
    *(bf16x8*)(Wpk + (size_t)o * 8) = w;
}

__global__ void init_ws(bf16_t* __restrict__ hbuf, unsigned int* __restrict__ bar) {
    int idx = blockIdx.x * 256 + threadIdx.x;
    if (idx < 2 * BATCH * D_OUT) hbuf[idx] = (bf16_t)0.0f;   // h0 = 0 (both buffers)
    if (idx < 512) bar[idx] = 0u;                            // barrier counters
}

// Persistent LSTM: 256 blocks (1/CU) x 256 threads, all 512 timesteps inside.
// Block = (mblk = bid>>6) batch quarter [32 rows] x (dblk = bid&63) 16 dims x 4 gates.
// Wave w owns K slice [w*512, w*512+512).
__global__ __launch_bounds__(256, 1)
void lstm_persist(const float* __restrict__ tokens,
                  const bf16_t* __restrict__ Wpk,
                  const float* __restrict__ bfp, const float* __restrict__ bip,
                  const float* __restrict__ bcp, const float* __restrict__ bop,
                  bf16_t* __restrict__ hbuf,
                  float* __restrict__ out,
                  unsigned int* __restrict__ bar)
{
    __shared__ bf16_t xh[32][2056];        // [batch row][k]; stride 4112 B: 16B-aligned, 2-way banks
    __shared__ float  preA[4][32][17];     // waves 0+1 partials [gate][b][j]
    __shared__ float  preB[4][32][17];     // waves 2+3 partials

    const int tid  = threadIdx.x;
    const int bid  = blockIdx.x;
    const int dblk = bid & 63;
    const int mblk = bid >> 6;
    const int m0   = mblk * 32;
    const int wave = tid >> 6;
    const int lane = tid & 63;
    const int l15  = lane & 15;
    const int q    = lane >> 4;

    // epilogue role: this thread owns (b = eb, eb+16 ; dim j = ej) forever -> c in registers
    const int ej = tid & 15;
    const int eb = tid >> 4;               // 0..15
    const int d  = dblk * 16 + ej;
    const float bj_f = bfp[d], bj_i = bip[d], bj_c = bcp[d], bj_o = bop[d];
    float c0 = 0.0f, c1 = 0.0f;

    // per-wave weight stream base: elems; loadB(g, ks) = wbase + g*32768 + ks*512
    const bf16_t* wbase = Wpk + (size_t)dblk * 131072 + (size_t)wave * 8192 + lane * 8;
    // A fragment bases in LDS (mt0 rows 0..15, mt1 rows 16..31)
    const bf16_t* aptr0 = &xh[l15][wave * 512 + q * 8];
    const bf16_t* aptr1 = &xh[16 + l15][wave * 512 + q * 8];

    unsigned int* shard = bar + (bid & 7) * 32;   // 128 B apart
    unsigned int* root  = bar + 256;

    const f32x4 fzero = {0.f, 0.f, 0.f, 0.f};

    auto pre_store = [&](float (*P)[32][17], f32x4 (&acc)[2][4]) {
        #pragma unroll
        for (int mt = 0; mt < 2; ++mt)
            #pragma unroll
            for (int g = 0; g < 4; ++g)
                #pragma unroll
                for (int i = 0; i < 4; ++i)
                    P[g][mt * 16 + q * 4 + i][l15] = acc[mt][g][i];
    };
    auto pre_add = [&](float (*P)[32][17], f32x4 (&acc)[2][4]) {
        #pragma unroll
        for (int mt = 0; mt < 2; ++mt)
            #pragma unroll
            for (int g = 0; g < 4; ++g)
                #pragma unroll
                for (int i = 0; i < 4; ++i)
                    P[g][mt * 16 + q * 4 + i][l15] += acc[mt][g][i];
    };

    for (int t = 0; t < T_SEQ; ++t) {
        const bf16_t* hb_cur = hbuf + (size_t)(t & 1) * (BATCH * D_OUT);
        bf16_t*       hb_nxt = hbuf + (size_t)((t + 1) & 1) * (BATCH * D_OUT);

        // ---- release h writes of step t-1 (epilogue synced last iter) + arrive ----
        if (tid == 0) {
            __threadfence();               // wb dirty L2 -> coherence point
            atomicAdd(shard, 1u);
        }

        // ---- stage x_t into LDS (fp32->bf16); no cross-block dependency: hides barrier ----
        {
            const float* xsrc = tokens + (size_t)t * (BATCH * D_IN) + (size_t)m0 * D_IN;
            #pragma unroll
            for (int it = 0; it < 16; ++it) {
                int idx = it * 256 + tid;
                int row = idx >> 7;
                int c8  = idx & 127;
                const float* s = xsrc + (size_t)row * D_IN + c8 * 8;
                float4 v0 = *(const float4*)s;
                float4 v1 = *(const float4*)(s + 4);
                bf16x8 w;
                w[0] = (bf16_t)v0.x; w[1] = (bf16_t)v0.y; w[2] = (bf16_t)v0.z; w[3] = (bf16_t)v0.w;
                w[4] = (bf16_t)v1.x; w[5] = (bf16_t)v1.y; w[6] = (bf16_t)v1.z; w[7] = (bf16_t)v1.w;
                *(bf16x8*)&xh[row][c8 * 8] = w;
            }
        }

        // ---- prefetch first 3 k-steps of weights into registers (static data) ----
        bf16x8 bpf[3][4];
        #pragma unroll
        for (int pk = 0; pk < 3; ++pk)
            #pragma unroll
            for (int g = 0; g < 4; ++g)
                bpf[pk][g] = *(const bf16x8*)(wbase + g * 32768 + pk * 512);

        // ---- wait for all 256 blocks (2-level monotonic counter barrier) ----
        if (tid == 0) {
            if (bid < 8) {
                while (__hip_atomic_load(shard, __ATOMIC_RELAXED, __HIP_MEMORY_SCOPE_AGENT)
                       < 32u * (unsigned)(t + 1)) {}
                atomicAdd(root, 1u);
            }
            while (__hip_atomic_load(root, __ATOMIC_RELAXED, __HIP_MEMORY_SCOPE_AGENT)
                   < 8u * (unsigned)(t + 1)) {}
            __threadfence();               // acquire: invalidate stale L1/L2 before reading h
        }
        __syncthreads();

        // ---- stage h_t (bf16, written by all blocks last step) ----
        #pragma unroll
        for (int it = 0; it < 16; ++it) {
            int idx = it * 256 + tid;
            int row = idx >> 7;
            int c8  = idx & 127;
            uint4 v = *(const uint4*)(hb_cur + (size_t)(m0 + row) * D_OUT + c8 * 8);
            *(uint4*)&xh[row][1024 + c8 * 8] = v;
        }
        __syncthreads();

        // ---- K loop: 16 k-steps x 32, zero barriers, B streamed from L2 3-deep ----
        f32x4 acc[2][4];
        #pragma unroll
        for (int mt = 0; mt < 2; ++mt)
            #pragma unroll
            for (int g = 0; g < 4; ++g)
                acc[mt][g] = fzero;

        bf16x8 apf[2][2];
        apf[0][0] = *(const bf16x8*)aptr0;
        apf[0][1] = *(const bf16x8*)aptr1;
        apf[1][0] = *(const bf16x8*)(aptr0 + 32);
        apf[1][1] = *(const bf16x8*)(aptr1 + 32);

        #pragma unroll
        for (int ks = 0; ks < 16; ++ks) {
            bf16x8 a0 = apf[ks & 1][0];
            bf16x8 a1 = apf[ks & 1][1];
            bf16x8 b0 = bpf[ks % 3][0];
            bf16x8 b1 = bpf[ks % 3][1];
            bf16x8 b2 = bpf[ks % 3][2];
            bf16x8 b3 = bpf[ks % 3][3];
            if (ks < 14) {
                apf[ks & 1][0] = *(const bf16x8*)(aptr0 + (ks + 2) * 32);
                apf[ks & 1][1] = *(const bf16x8*)(aptr1 + (ks + 2) * 32);
            }
            if (ks < 13) {
                #pragma unroll
                for (int g = 0; g < 4; ++g)
                    bpf[ks % 3][g] = *(const bf16x8*)(wbase + g * 32768 + (ks + 3) * 512);
            }
            acc[0][0] = __builtin_amdgcn_mfma_f32_16x16x32_bf16(a0, b0, acc[0][0], 0, 0, 0);
            acc[1][0] = __builtin_amdgcn_mfma_f32_16x16x32_bf16(a1, b0, acc[1][0], 0, 0, 0);
            acc[0][1] = __builtin_amdgcn_mfma_f32_16x16x32_bf16(a0, b1, acc[0][1], 0, 0, 0);
            acc[1][1] = __builtin_amdgcn_mfma_f32_16x16x32_bf16(a1, b1, acc[1][1], 0, 0, 0);
            acc[0][2] = __builtin_amdgcn_mfma_f32_16x16x32_bf16(a0, b2, acc[0][2], 0, 0, 0);
            acc[1][2] = __builtin_amdgcn_mfma_f32_16x16x32_bf16(a1, b2, acc[1][2], 0, 0, 0);
            acc[0][3] = __builtin_amdgcn_mfma_f32_16x16x32_bf16(a0, b3, acc[0][3], 0, 0, 0);
            acc[1][3] = __builtin_amdgcn_mfma_f32_16x16x32_bf16(a1, b3, acc[1][3], 0, 0, 0);
        }

        // ---- deterministic cross-wave K reduction (no atomics) ----
        if (wave == 0)      pre_store(preA, acc);
        else if (wave == 2) pre_store(preB, acc);
        __syncthreads();
        if (wave == 1)      pre_add(preA, acc);
        else if (wave == 3) pre_add(preB, acc);
        __syncthreads();

        // ---- pointwise epilogue: c in registers, h -> global ping-pong + out ----
        float* out_t = out + (size_t)t * (BATCH * D_OUT);
        {
            float pf = preA[0][eb][ej] + preB[0][eb][ej] + bj_f;
            float pi = preA[1][eb][ej] + preB[1][eb][ej] + bj_i;
            float pc = preA[2][eb][ej] + preB[2][eb][ej] + bj_c;
            float po = preA[3][eb][ej] + preB[3][eb][ej] + bj_o;
            float fg = sigm(pf), ig = sigm(pi), gg = tanh_f(pc), og = sigm(po);
            c0 = c0 * fg + ig * gg;
            float h = og * tanh_f(c0);
            size_t off = (size_t)(m0 + eb) * D_OUT + d;
            __builtin_nontemporal_store(h, out_t + off);
            hb_nxt[off] = (bf16_t)h;
        }
        {
            int b2 = eb + 16;
            float pf = preA[0][b2][ej] + preB[0][b2][ej] + bj_f;
            float pi = preA[1][b2][ej] + preB[1][b2][ej] + bj_i;
            float pc = preA[2][b2][ej] + preB[2][b2][ej] + bj_c;
            float po = preA[3][b2][ej] + preB[3][b2][ej] + bj_o;
            float fg = sigm(pf), ig = sigm(pi), gg = tanh_f(pc), og = sigm(po);
            c1 = c1 * fg + ig * gg;
            float h = og * tanh_f(c1);
            size_t off = (size_t)(m0 + b2) * D_OUT + d;
            __builtin_nontemporal_store(h, out_t + off);
            hb_nxt[off] = (bf16_t)h;
        }
        __syncthreads();   // drain all waves' h stores before next-iter release/arrive
    }
}

extern "C" void kernel_launch(void* const* d_in, const int* in_sizes, int n_in,
                              void* d_out, int out_size, void* d_ws, size_t ws_size,
                              hipStream_t stream) {
    (void)in_sizes; (void)n_in; (void)out_size; (void)ws_size;
    const float* tokens = (const float*)d_in[0];
    const float* Wf = (const float*)d_in[1];
    const float* bf_ = (const float*)d_in[2];
    const float* Wi = (const float*)d_in[3];
    const float* bi_ = (const float*)d_in[4];
    const float* Wc = (const float*)d_in[5];
    const float* bc_ = (const float*)d_in[6];
    const float* Wo = (const float*)d_in[7];
    const float* bo_ = (const float*)d_in[8];
    float* out = (float*)d_out;

    char* ws = (char*)d_ws;
    bf16_t*       Wpk  = (bf16_t*)(ws + WS_WPK);
    bf16_t*       hbuf = (bf16_t*)(ws + WS_H);
    unsigned int* bar  = (unsigned int*)(ws + WS_BAR);

    pack_weights<<<4096, 256, 0, stream>>>(Wf, Wi, Wc, Wo, Wpk);
    init_ws<<<1024, 256, 0, stream>>>(hbuf, bar);

    void* args[] = {(void*)&tokens, (void*)&Wpk, (void*)&bf_, (void*)&bi_,
                    (void*)&bc_, (void*)&bo_, (void*)&hbuf, (void*)&out, (void*)&bar};
    hipError_t e = hipLaunchCooperativeKernel(reinterpret_cast<const void*>(&lstm_persist),
                                              dim3(256), dim3(256), args, 0u, stream);
    if (e != hipSuccess) {
        // capacity-safe fallback: 256 blocks x 148,992 B LDS => exactly 1 block/CU on 256 CUs
        lstm_persist<<<256, 256, 0, stream>>>(tokens, Wpk, bf_, bi_, bc_, bo_, hbuf, out, bar);
    }
}